// Round 6
// baseline (582.843 us; speedup 1.0000x reference)
//
#include <hip/hip_runtime.h>

#define N_NODES 100000
#define N_EDGES 3200000
#define IN_FEAT 512
#define HID 16
#define BNODES 128                        // nodes per bucket (dst >> 7)
#define NB 782                            // ceil(100000/128)
#define CHUNK 8192
#define NCHUNKS ((N_EDGES + CHUNK - 1) / CHUNK)   // 391
#define PAD 1024                          // bucket ranges padded to PAD
#define SENT ((unsigned)((N_NODES << 7) | 127))   // sentinel: zero-row, ld=127

typedef float f32x4 __attribute__((ext_vector_type(4)));

// ---------------------------------------------------------------------------
// Edge-index dtype hedge (int64 vs int32 storage), probed device-side.
// ---------------------------------------------------------------------------
__global__ void k_detect(const void* ei, int* flag) {
    const int* p = (const int*)ei;
    int t = threadIdx.x;                     // 64 threads = 1 wave
    bool nz = (p[2 * t + 1] != 0);
    unsigned long long m = __ballot(nz);
    if (t == 0) *flag = (m == 0ull) ? 1 : 0; // 1 => int64 storage
}

__device__ __forceinline__ int load_dst(const void* ei, int is64, int e) {
    if (is64) return (int)((const long long*)ei)[(long long)N_EDGES + e];
    return ((const int*)ei)[N_EDGES + e];
}
__device__ __forceinline__ int load_src(const void* ei, int is64, int e) {
    if (is64) return (int)((const long long*)ei)[e];
    return ((const int*)ei)[e];
}

// ---- bucket histogram ------------------------------------------------------
__global__ void k_hist(const void* ei, const int* __restrict__ flag,
                       int* __restrict__ ghist) {
    __shared__ int h[NB];
    int tid = threadIdx.x;
    int is64 = *flag;
    for (int i = tid; i < NB; i += 256) h[i] = 0;
    __syncthreads();
    for (int e = blockIdx.x * 256 + tid; e < N_EDGES; e += gridDim.x * 256)
        atomicAdd(&h[load_dst(ei, is64, e) >> 7], 1);
    __syncthreads();
    for (int i = tid; i < NB; i += 256)
        if (h[i]) atomicAdd(&ghist[i], h[i]);
}

// ---- exclusive scan of PADDED bucket counts (one block) --------------------
__global__ __launch_bounds__(1024)
void k_scan(const int* __restrict__ ghist, int* __restrict__ goff,
            int* __restrict__ gcursor) {
    __shared__ int s[1024];
    int tid = threadIdx.x;
    int g = (tid < NB) ? ghist[tid] : 0;
    int v = ((g + PAD - 1) / PAD) * PAD;   // padded count
    s[tid] = v;
    __syncthreads();
    for (int o = 1; o < 1024; o <<= 1) {
        int t = (tid >= o) ? s[tid - o] : 0;
        __syncthreads();
        s[tid] += t;
        __syncthreads();
    }
    int excl = s[tid] - v;
    if (tid <= NB) goff[tid] = excl;
    if (tid < NB) gcursor[tid] = excl;
}

// ---- per-chunk LDS counting sort + coalesced bucketed scatter --------------
// entry = src<<7 | (dst & 127); bucket = dst>>7
__global__ __launch_bounds__(1024)
void k_sortscatter(const void* ei, const int* __restrict__ flag,
                   int* __restrict__ gcursor, unsigned* __restrict__ colp) {
    __shared__ unsigned sorted[CHUNK];     // 32 KB
    __shared__ int hist[1024];             // doubles as cursor
    __shared__ int scanL[1024];
    __shared__ int gbase[1024];
    int tid = threadIdx.x;
    int base = blockIdx.x * CHUNK;
    int chunkN = min(CHUNK, N_EDGES - base);
    int is64 = *flag;

    hist[tid] = 0;
    __syncthreads();

    unsigned ent[8];
    short bkt[8];
#pragma unroll
    for (int k = 0; k < 8; ++k) {
        int i = k * 1024 + tid;
        if (i < chunkN) {
            int e = base + i;
            int s = load_src(ei, is64, e);
            int d = load_dst(ei, is64, e);
            int b = d >> 7;
            ent[k] = ((unsigned)s << 7) | (unsigned)(d & 127);
            bkt[k] = (short)b;
            atomicAdd(&hist[b], 1);
        } else bkt[k] = -1;
    }
    __syncthreads();

    int v = hist[tid];
    scanL[tid] = v;
    __syncthreads();
    for (int o = 1; o < 1024; o <<= 1) {
        int t = (tid >= o) ? scanL[tid - o] : 0;
        __syncthreads();
        scanL[tid] += t;
        __syncthreads();
    }
    int excl = scanL[tid] - v;
    __syncthreads();
    scanL[tid] = excl;                     // scanL[NB] == chunkN automatically
    hist[tid] = 0;                         // reuse as within-bucket cursor
    __syncthreads();

#pragma unroll
    for (int k = 0; k < 8; ++k) {
        if (bkt[k] >= 0) {
            int b = bkt[k];
            int pos = atomicAdd(&hist[b], 1);
            sorted[scanL[b] + pos] = ent[k];
        }
    }
    __syncthreads();

    if (tid < NB) {
        int cnt = scanL[tid + 1] - scanL[tid];
        gbase[tid] = (cnt > 0) ? atomicAdd(&gcursor[tid], cnt) : 0;
    }
    __syncthreads();

    for (int i = tid; i < chunkN; i += 1024) {
        int lo = 0, hi = NB;               // invariant: scanL[lo] <= i < scanL[hi]
        while (hi - lo > 1) {
            int mid = (lo + hi) >> 1;
            if (scanL[mid] <= i) lo = mid; else hi = mid;
        }
        colp[gbase[lo] + (i - scanL[lo])] = sorted[i];
    }
}

// ---- fill the padding gap of each bucket with sentinels --------------------
__global__ void k_padfill(const int* __restrict__ goff, const int* __restrict__ ghist,
                          unsigned* __restrict__ colp) {
    int b = blockIdx.x;
    int start = goff[b] + ghist[b];
    int end = goff[b + 1];
    for (int i = start + threadIdx.x; i < end; i += blockDim.x)
        colp[i] = SENT;
}

// ---- degree (from bucketed entries, real range only) -> dinv ---------------
__global__ void k_degdinv(const int* __restrict__ goff, const int* __restrict__ ghist,
                          const unsigned* __restrict__ colp,
                          float* __restrict__ dinv) {
    __shared__ int cnt[BNODES];
    int b = blockIdx.x, tid = threadIdx.x;
    if (tid < BNODES) cnt[tid] = 0;
    __syncthreads();
    int s0 = goff[b], s1 = goff[b] + ghist[b];
    for (int i = s0 + tid; i < s1; i += 256)
        atomicAdd(&cnt[colp[i] & 127], 1);
    __syncthreads();
    if (tid < BNODES) {
        int node = (b << 7) + tid;
        if (node < N_NODES) dinv[node] = rsqrtf((float)(cnt[tid] + 1));
    }
}

// ---- xws = (x @ W1) * dinv[row] -------------------------------------------
__global__ void k_gemm1(const float* __restrict__ x, const float* __restrict__ W1,
                        const float* __restrict__ dinv, float* __restrict__ xws) {
    int row = blockIdx.x * blockDim.x + threadIdx.x;
    if (row >= N_NODES) return;
    const float4* xr = (const float4*)(x + (size_t)row * IN_FEAT);
    float acc[16];
#pragma unroll
    for (int f = 0; f < 16; ++f) acc[f] = 0.f;

#pragma unroll 1
    for (int k0 = 0; k0 < IN_FEAT; k0 += 16) {
        float4 v0 = xr[k0 / 4 + 0];
        float4 v1 = xr[k0 / 4 + 1];
        float4 v2 = xr[k0 / 4 + 2];
        float4 v3 = xr[k0 / 4 + 3];
        float xv[16] = {v0.x, v0.y, v0.z, v0.w, v1.x, v1.y, v1.z, v1.w,
                        v2.x, v2.y, v2.z, v2.w, v3.x, v3.y, v3.z, v3.w};
#pragma unroll
        for (int kk = 0; kk < 16; ++kk) {
            const float* wr = W1 + (size_t)(k0 + kk) * HID;
#pragma unroll
            for (int f = 0; f < HID; ++f)
                acc[f] = fmaf(xv[kk], wr[f], acc[f]);
        }
    }
    float di = dinv[row];
    float4* xv4 = (float4*)(xws + (size_t)row * HID);
#pragma unroll
    for (int q = 0; q < 4; ++q)
        xv4[q] = make_float4(acc[4 * q] * di, acc[4 * q + 1] * di,
                             acc[4 * q + 2] * di, acc[4 * q + 3] * di);
}

// ---- layer-1 aggregation: 4 lanes/edge, 8 gathers in flight via inline asm -
// out1 = relu(b1 + dinv*(self + sum_{src->d} xws[src]))
#define A1_STRIDE 17                       // LDS row stride (bank decorrelation)
__global__ __launch_bounds__(512)
void k_aggr1(const int* __restrict__ goff, const unsigned* __restrict__ colp,
             const float* __restrict__ dinv, const float* __restrict__ xws,
             const float* __restrict__ b1, float* __restrict__ out1) {
    __shared__ float acc[BNODES * A1_STRIDE];    // 8.5 KB
    int b = blockIdx.x, tid = threadIdx.x;
    int es = tid >> 2;                     // 0..127 edge-slot
    int q  = tid & 3;                      // float4 quarter
    const f32x4* xws4 = (const f32x4*)xws;
    for (int i = tid; i < BNODES * A1_STRIDE; i += 512) acc[i] = 0.f;
    __syncthreads();
    int s0 = goff[b], s1 = goff[b + 1];    // padded: multiple of 1024
    for (int i0 = s0; i0 < s1; i0 += PAD) {
        // 8 edges per edge-slot, entries loaded with 2 coalesced uint4 reads
        const uint4* cp = (const uint4*)(colp + i0 + es * 8);
        uint4 eA = cp[0];
        uint4 eB = cp[1];
        const f32x4* p0 = xws4 + ((size_t)(eA.x >> 7) * 4 + q);
        const f32x4* p1 = xws4 + ((size_t)(eA.y >> 7) * 4 + q);
        const f32x4* p2 = xws4 + ((size_t)(eA.z >> 7) * 4 + q);
        const f32x4* p3 = xws4 + ((size_t)(eA.w >> 7) * 4 + q);
        const f32x4* p4 = xws4 + ((size_t)(eB.x >> 7) * 4 + q);
        const f32x4* p5 = xws4 + ((size_t)(eB.y >> 7) * 4 + q);
        const f32x4* p6 = xws4 + ((size_t)(eB.z >> 7) * 4 + q);
        const f32x4* p7 = xws4 + ((size_t)(eB.w >> 7) * 4 + q);
        f32x4 v0, v1, v2, v3, v4, v5, v6, v7;
        // 8 independent 16B gathers issued back-to-back, ONE wait.
        asm volatile(
            "global_load_dwordx4 %0, %8, off\n\t"
            "global_load_dwordx4 %1, %9, off\n\t"
            "global_load_dwordx4 %2, %10, off\n\t"
            "global_load_dwordx4 %3, %11, off\n\t"
            "global_load_dwordx4 %4, %12, off\n\t"
            "global_load_dwordx4 %5, %13, off\n\t"
            "global_load_dwordx4 %6, %14, off\n\t"
            "global_load_dwordx4 %7, %15, off\n\t"
            "s_waitcnt vmcnt(0)"
            : "=&v"(v0), "=&v"(v1), "=&v"(v2), "=&v"(v3),
              "=&v"(v4), "=&v"(v5), "=&v"(v6), "=&v"(v7)
            : "v"(p0), "v"(p1), "v"(p2), "v"(p3),
              "v"(p4), "v"(p5), "v"(p6), "v"(p7));
        int qb = q * 4;
        float* a;
        a = &acc[(int)(eA.x & 127u) * A1_STRIDE + qb];
        atomicAdd(a + 0, v0.x); atomicAdd(a + 1, v0.y);
        atomicAdd(a + 2, v0.z); atomicAdd(a + 3, v0.w);
        a = &acc[(int)(eA.y & 127u) * A1_STRIDE + qb];
        atomicAdd(a + 0, v1.x); atomicAdd(a + 1, v1.y);
        atomicAdd(a + 2, v1.z); atomicAdd(a + 3, v1.w);
        a = &acc[(int)(eA.z & 127u) * A1_STRIDE + qb];
        atomicAdd(a + 0, v2.x); atomicAdd(a + 1, v2.y);
        atomicAdd(a + 2, v2.z); atomicAdd(a + 3, v2.w);
        a = &acc[(int)(eA.w & 127u) * A1_STRIDE + qb];
        atomicAdd(a + 0, v3.x); atomicAdd(a + 1, v3.y);
        atomicAdd(a + 2, v3.z); atomicAdd(a + 3, v3.w);
        a = &acc[(int)(eB.x & 127u) * A1_STRIDE + qb];
        atomicAdd(a + 0, v4.x); atomicAdd(a + 1, v4.y);
        atomicAdd(a + 2, v4.z); atomicAdd(a + 3, v4.w);
        a = &acc[(int)(eB.y & 127u) * A1_STRIDE + qb];
        atomicAdd(a + 0, v5.x); atomicAdd(a + 1, v5.y);
        atomicAdd(a + 2, v5.z); atomicAdd(a + 3, v5.w);
        a = &acc[(int)(eB.z & 127u) * A1_STRIDE + qb];
        atomicAdd(a + 0, v6.x); atomicAdd(a + 1, v6.y);
        atomicAdd(a + 2, v6.z); atomicAdd(a + 3, v6.w);
        a = &acc[(int)(eB.w & 127u) * A1_STRIDE + qb];
        atomicAdd(a + 0, v7.x); atomicAdd(a + 1, v7.y);
        atomicAdd(a + 2, v7.z); atomicAdd(a + 3, v7.w);
    }
    __syncthreads();
    {   // writeout: thread = (r, q)
        int r = tid >> 2;
        int node = (b << 7) + r;
        if (node < N_NODES) {
            float di = dinv[node];
            f32x4 self = xws4[(size_t)node * 4 + q];
            const float* a = &acc[r * A1_STRIDE + q * 4];
            float4 o;
            o.x = fmaxf(fmaf(di, a[0] + self.x, b1[q * 4 + 0]), 0.f);
            o.y = fmaxf(fmaf(di, a[1] + self.y, b1[q * 4 + 1]), 0.f);
            o.z = fmaxf(fmaf(di, a[2] + self.z, b1[q * 4 + 2]), 0.f);
            o.w = fmaxf(fmaf(di, a[3] + self.w, b1[q * 4 + 3]), 0.f);
            ((float4*)out1)[(size_t)node * 4 + q] = o;
        }
    }
}

// ---- h2s = (out1 @ W2) * dinv ---------------------------------------------
__global__ void k_layer2(const float* __restrict__ out1, const float* __restrict__ W2,
                         const float* __restrict__ dinv, float* __restrict__ h2s) {
    int i = blockIdx.x * blockDim.x + threadIdx.x;
    if (i >= N_NODES) return;
    const float4* hv = (const float4*)(out1 + (size_t)i * HID);
    float g0 = 0.f, g1 = 0.f;
#pragma unroll
    for (int q = 0; q < 4; ++q) {
        float4 v = hv[q];
        g0 = fmaf(v.x, W2[(4 * q + 0) * 2 + 0], g0);
        g1 = fmaf(v.x, W2[(4 * q + 0) * 2 + 1], g1);
        g0 = fmaf(v.y, W2[(4 * q + 1) * 2 + 0], g0);
        g1 = fmaf(v.y, W2[(4 * q + 1) * 2 + 1], g1);
        g0 = fmaf(v.z, W2[(4 * q + 2) * 2 + 0], g0);
        g1 = fmaf(v.z, W2[(4 * q + 2) * 2 + 1], g1);
        g0 = fmaf(v.w, W2[(4 * q + 3) * 2 + 0], g0);
        g1 = fmaf(v.w, W2[(4 * q + 3) * 2 + 1], g1);
    }
    float di = dinv[i];
    ((float2*)h2s)[i] = make_float2(g0 * di, g1 * di);
}

// ---- layer-2 aggregation + log_softmax, 4 asm-batched gathers --------------
#define A2_STRIDE 3
__global__ __launch_bounds__(512)
void k_aggr2(const int* __restrict__ goff, const unsigned* __restrict__ colp,
             const float* __restrict__ dinv, const float* __restrict__ h2s,
             const float* __restrict__ b2, float* __restrict__ y) {
    __shared__ float acc[BNODES * A2_STRIDE];
    int b = blockIdx.x, tid = threadIdx.x;
    int c = tid & 1;
    int eg = tid >> 1;                     // 0..255
    for (int i = tid; i < BNODES * A2_STRIDE; i += 512) acc[i] = 0.f;
    __syncthreads();
    int s0 = goff[b], s1 = goff[b + 1];    // padded: multiple of 1024
    for (int i0 = s0; i0 < s1; i0 += PAD) {
        uint4 eA = *(const uint4*)(colp + i0 + eg * 4);
        const float* p0 = h2s + ((size_t)(eA.x >> 7) * 2 + c);
        const float* p1 = h2s + ((size_t)(eA.y >> 7) * 2 + c);
        const float* p2 = h2s + ((size_t)(eA.z >> 7) * 2 + c);
        const float* p3 = h2s + ((size_t)(eA.w >> 7) * 2 + c);
        float v0, v1, v2, v3;
        asm volatile(
            "global_load_dword %0, %4, off\n\t"
            "global_load_dword %1, %5, off\n\t"
            "global_load_dword %2, %6, off\n\t"
            "global_load_dword %3, %7, off\n\t"
            "s_waitcnt vmcnt(0)"
            : "=&v"(v0), "=&v"(v1), "=&v"(v2), "=&v"(v3)
            : "v"(p0), "v"(p1), "v"(p2), "v"(p3));
        atomicAdd(&acc[(int)(eA.x & 127u) * A2_STRIDE + c], v0);
        atomicAdd(&acc[(int)(eA.y & 127u) * A2_STRIDE + c], v1);
        atomicAdd(&acc[(int)(eA.z & 127u) * A2_STRIDE + c], v2);
        atomicAdd(&acc[(int)(eA.w & 127u) * A2_STRIDE + c], v3);
    }
    __syncthreads();
    if (tid < BNODES * 2) {
        int r = tid >> 1;
        int node = (b << 7) + r;
        if (node < N_NODES) {
            float v = fmaf(dinv[node], acc[r * A2_STRIDE + c] + h2s[(size_t)node * 2 + c], b2[c]);
            float o = __shfl_xor(v, 1);
            float m = fmaxf(v, o);
            float lse = m + logf(expf(v - m) + expf(o - m));
            y[(size_t)node * 2 + c] = v - lse;
        }
    }
}

extern "C" void kernel_launch(void* const* d_in, const int* in_sizes, int n_in,
                              void* d_out, int out_size, void* d_ws, size_t ws_size,
                              hipStream_t stream) {
    const float* x  = (const float*)d_in[0];
    const void*  ei = d_in[1];
    const float* W1 = (const float*)d_in[2];
    const float* b1 = (const float*)d_in[3];
    const float* W2 = (const float*)d_in[4];
    const float* b2 = (const float*)d_in[5];
    float* y = (float*)d_out;

    char* w = (char*)d_ws;
    int*      flag    = (int*)(w + 0);
    int*      ghist   = (int*)(w + 1024);        // 3128 B
    int*      goff    = (int*)(w + 8192);        // 3132 B
    int*      gcursor = (int*)(w + 16384);       // 3128 B
    float*    dinv    = (float*)(w + 24576);     // 400 KB
    unsigned* colp    = (unsigned*)(w + 425984); // <= 16.1 MB (padded)
    float*    xws     = (float*)(w + 17426432);  // (N+1) rows = 6.4 MB
    float*    out1    = (float*)(w + 23826496);  // 6.4 MB
    float*    h2s     = (float*)(w + 30226496);  // (N+1)*2 floats
    // end ~31.0 MB

    hipMemsetAsync(ghist, 0, NB * sizeof(int), stream);
    hipMemsetAsync(xws + (size_t)N_NODES * HID, 0, HID * sizeof(float), stream);
    hipMemsetAsync(h2s + (size_t)N_NODES * 2, 0, 2 * sizeof(float), stream);
    k_detect<<<1, 64, 0, stream>>>(ei, flag);
    k_hist<<<512, 256, 0, stream>>>(ei, flag, ghist);
    k_scan<<<1, 1024, 0, stream>>>(ghist, goff, gcursor);
    k_sortscatter<<<NCHUNKS, 1024, 0, stream>>>(ei, flag, gcursor, colp);
    k_padfill<<<NB, 256, 0, stream>>>(goff, ghist, colp);
    k_degdinv<<<NB, 256, 0, stream>>>(goff, ghist, colp, dinv);
    k_gemm1<<<(N_NODES + 255) / 256, 256, 0, stream>>>(x, W1, dinv, xws);
    k_aggr1<<<NB, 512, 0, stream>>>(goff, colp, dinv, xws, b1, out1);
    k_layer2<<<(N_NODES + 255) / 256, 256, 0, stream>>>(out1, W2, dinv, h2s);
    k_aggr2<<<NB, 512, 0, stream>>>(goff, colp, dinv, h2s, b2, y);
}

// Round 7
// 198.799 us; speedup vs baseline: 2.9318x; 2.9318x over previous
//
#include <hip/hip_runtime.h>

#define N_NODES 100000
#define N_EDGES 3200000
#define IN_FEAT 512
#define HID 16
#define BNODES 128                        // nodes per bucket (dst >> 7)
#define NB 782                            // ceil(100000/128)
#define CHUNK 8192
#define NCHUNKS ((N_EDGES + CHUNK - 1) / CHUNK)   // 391

typedef float f32x4 __attribute__((ext_vector_type(4)));

// ---------------------------------------------------------------------------
// Edge-index dtype hedge (int64 vs int32 storage), probed device-side.
// ---------------------------------------------------------------------------
__global__ void k_detect(const void* ei, int* flag) {
    const int* p = (const int*)ei;
    int t = threadIdx.x;                     // 64 threads = 1 wave
    bool nz = (p[2 * t + 1] != 0);
    unsigned long long m = __ballot(nz);
    if (t == 0) *flag = (m == 0ull) ? 1 : 0; // 1 => int64 storage
}

__device__ __forceinline__ int load_dst(const void* ei, int is64, int e) {
    if (is64) return (int)((const long long*)ei)[(long long)N_EDGES + e];
    return ((const int*)ei)[N_EDGES + e];
}
__device__ __forceinline__ int load_src(const void* ei, int is64, int e) {
    if (is64) return (int)((const long long*)ei)[e];
    return ((const int*)ei)[e];
}

// ---- bucket histogram (int atomics: native) --------------------------------
__global__ void k_hist(const void* ei, const int* __restrict__ flag,
                       int* __restrict__ ghist) {
    __shared__ int h[NB];
    int tid = threadIdx.x;
    int is64 = *flag;
    for (int i = tid; i < NB; i += 256) h[i] = 0;
    __syncthreads();
    for (int e = blockIdx.x * 256 + tid; e < N_EDGES; e += gridDim.x * 256)
        atomicAdd(&h[load_dst(ei, is64, e) >> 7], 1);
    __syncthreads();
    for (int i = tid; i < NB; i += 256)
        if (h[i]) atomicAdd(&ghist[i], h[i]);
}

// ---- exclusive scan over NB buckets (one block) ----------------------------
__global__ __launch_bounds__(1024)
void k_scan(const int* __restrict__ ghist, int* __restrict__ goff,
            int* __restrict__ gcursor) {
    __shared__ int s[1024];
    int tid = threadIdx.x;
    int v = (tid < NB) ? ghist[tid] : 0;
    s[tid] = v;
    __syncthreads();
    for (int o = 1; o < 1024; o <<= 1) {
        int t = (tid >= o) ? s[tid - o] : 0;
        __syncthreads();
        s[tid] += t;
        __syncthreads();
    }
    int excl = s[tid] - v;                 // tid==NB -> total (v==0 there)
    if (tid <= NB) goff[tid] = excl;
    if (tid < NB) gcursor[tid] = excl;
}

// ---- per-chunk LDS counting sort + coalesced bucketed scatter --------------
// entry = src<<7 | (dst & 127); bucket = dst>>7
__global__ __launch_bounds__(1024)
void k_sortscatter(const void* ei, const int* __restrict__ flag,
                   int* __restrict__ gcursor, unsigned* __restrict__ colp) {
    __shared__ unsigned sorted[CHUNK];     // 32 KB
    __shared__ int hist[1024];             // doubles as cursor
    __shared__ int scanL[1024];
    __shared__ int gbase[1024];
    int tid = threadIdx.x;
    int base = blockIdx.x * CHUNK;
    int chunkN = min(CHUNK, N_EDGES - base);
    int is64 = *flag;

    hist[tid] = 0;
    __syncthreads();

    unsigned ent[8];
    short bkt[8];
#pragma unroll
    for (int k = 0; k < 8; ++k) {
        int i = k * 1024 + tid;
        if (i < chunkN) {
            int e = base + i;
            int s = load_src(ei, is64, e);
            int d = load_dst(ei, is64, e);
            int b = d >> 7;
            ent[k] = ((unsigned)s << 7) | (unsigned)(d & 127);
            bkt[k] = (short)b;
            atomicAdd(&hist[b], 1);
        } else bkt[k] = -1;
    }
    __syncthreads();

    int v = hist[tid];
    scanL[tid] = v;
    __syncthreads();
    for (int o = 1; o < 1024; o <<= 1) {
        int t = (tid >= o) ? scanL[tid - o] : 0;
        __syncthreads();
        scanL[tid] += t;
        __syncthreads();
    }
    int excl = scanL[tid] - v;
    __syncthreads();
    scanL[tid] = excl;                     // scanL[NB] == chunkN automatically
    hist[tid] = 0;                         // reuse as within-bucket cursor
    __syncthreads();

#pragma unroll
    for (int k = 0; k < 8; ++k) {
        if (bkt[k] >= 0) {
            int b = bkt[k];
            int pos = atomicAdd(&hist[b], 1);
            sorted[scanL[b] + pos] = ent[k];
        }
    }
    __syncthreads();

    if (tid < NB) {
        int cnt = scanL[tid + 1] - scanL[tid];
        gbase[tid] = (cnt > 0) ? atomicAdd(&gcursor[tid], cnt) : 0;
    }
    __syncthreads();

    for (int i = tid; i < chunkN; i += 1024) {
        int lo = 0, hi = NB;               // invariant: scanL[lo] <= i < scanL[hi]
        while (hi - lo > 1) {
            int mid = (lo + hi) >> 1;
            if (scanL[mid] <= i) lo = mid; else hi = mid;
        }
        colp[gbase[lo] + (i - scanL[lo])] = sorted[i];
    }
}

// ---- per-bucket counting sort by node: colp -> colf (full node CSR) --------
// also emits noff[node], dinv[node]. Only INT LDS atomics (native).
__global__ __launch_bounds__(256)
void k_nodecsr(const int* __restrict__ goff, const unsigned* __restrict__ colp,
               int* __restrict__ noff, int* __restrict__ colf,
               float* __restrict__ dinv) {
    __shared__ int hist[BNODES];
    __shared__ int base[BNODES];
    __shared__ int sc[256];
    int b = blockIdx.x, tid = threadIdx.x;
    if (tid < BNODES) hist[tid] = 0;
    __syncthreads();
    int s0 = goff[b], s1 = goff[b + 1];
    for (int i = s0 + tid; i < s1; i += 256)
        atomicAdd(&hist[colp[i] & 127u], 1);
    __syncthreads();
    int v = (tid < BNODES) ? hist[tid] : 0;
    sc[tid] = v;
    __syncthreads();
    for (int o = 1; o < 256; o <<= 1) {
        int t = (tid >= o) ? sc[tid - o] : 0;
        __syncthreads();
        sc[tid] += t;
        __syncthreads();
    }
    int excl = sc[tid] - v;
    if (tid < BNODES) {
        base[tid] = s0 + excl;
        int node = (b << 7) + tid;
        if (node < N_NODES) {
            noff[node] = s0 + excl;
            dinv[node] = rsqrtf((float)v + 1.0f);   // +1 self-loop
        }
    }
    if (b == NB - 1 && tid == 0) noff[N_NODES] = s1;
    __syncthreads();
    if (tid < BNODES) hist[tid] = 0;       // reuse as cursor
    __syncthreads();
    for (int i = s0 + tid; i < s1; i += 256) {
        unsigned e = colp[i];
        int ld = (int)(e & 127u);
        int pos = atomicAdd(&hist[ld], 1);
        colf[base[ld] + pos] = (int)(e >> 7);
    }
}

// ---- xws = (x @ W1) * dinv[row] -------------------------------------------
__global__ void k_gemm1(const float* __restrict__ x, const float* __restrict__ W1,
                        const float* __restrict__ dinv, float* __restrict__ xws) {
    int row = blockIdx.x * blockDim.x + threadIdx.x;
    if (row >= N_NODES) return;
    const float4* xr = (const float4*)(x + (size_t)row * IN_FEAT);
    float acc[16];
#pragma unroll
    for (int f = 0; f < 16; ++f) acc[f] = 0.f;

#pragma unroll 1
    for (int k0 = 0; k0 < IN_FEAT; k0 += 16) {
        float4 v0 = xr[k0 / 4 + 0];
        float4 v1 = xr[k0 / 4 + 1];
        float4 v2 = xr[k0 / 4 + 2];
        float4 v3 = xr[k0 / 4 + 3];
        float xv[16] = {v0.x, v0.y, v0.z, v0.w, v1.x, v1.y, v1.z, v1.w,
                        v2.x, v2.y, v2.z, v2.w, v3.x, v3.y, v3.z, v3.w};
#pragma unroll
        for (int kk = 0; kk < 16; ++kk) {
            const float* wr = W1 + (size_t)(k0 + kk) * HID;
#pragma unroll
            for (int f = 0; f < HID; ++f)
                acc[f] = fmaf(xv[kk], wr[f], acc[f]);
        }
    }
    float di = dinv[row];
    float4* xv4 = (float4*)(xws + (size_t)row * HID);
#pragma unroll
    for (int q = 0; q < 4; ++q)
        xv4[q] = make_float4(acc[4 * q] * di, acc[4 * q + 1] * di,
                             acc[4 * q + 2] * di, acc[4 * q + 3] * di);
}

// ---- layer-1 aggregation: 16 lanes/node, NO atomics ------------------------
// lane l walks edges start+l, start+16+l, ... loading full 64B xws rows into
// registers; butterfly transpose-reduce leaves lane l holding feature l.
__global__ __launch_bounds__(256)
void k_gather1(const int* __restrict__ noff, const int* __restrict__ colf,
               const float* __restrict__ dinv, const float* __restrict__ xws,
               const float* __restrict__ b1, float* __restrict__ out1) {
    int t = blockIdx.x * 256 + threadIdx.x;   // grid exactly N_NODES*16
    int node = t >> 4;
    int l = t & 15;
    int start = noff[node], end = noff[node + 1];
    const f32x4* xws4 = (const f32x4*)xws;
    float acc[16];
#pragma unroll
    for (int r = 0; r < 16; ++r) acc[r] = 0.f;
    for (int j = start; j < end; j += 16) {
        int jl = j + l;
        int jj = min(jl, end - 1);            // loop guarantees end-1 >= start
        int s = colf[jj];
        s = (jl < end) ? s : N_NODES;         // masked lanes -> zero row
        const f32x4* row = xws4 + (size_t)s * 4;
        f32x4 r0 = row[0], r1 = row[1], r2 = row[2], r3 = row[3];
        acc[0]  += r0.x; acc[1]  += r0.y; acc[2]  += r0.z; acc[3]  += r0.w;
        acc[4]  += r1.x; acc[5]  += r1.y; acc[6]  += r1.z; acc[7]  += r1.w;
        acc[8]  += r2.x; acc[9]  += r2.y; acc[10] += r2.z; acc[11] += r2.w;
        acc[12] += r3.x; acc[13] += r3.y; acc[14] += r3.z; acc[15] += r3.w;
    }
    // butterfly transpose-reduce: after 4 stages lane l holds sum of feature l
    float c8[8];
#pragma unroll
    for (int k = 0; k < 8; ++k) {
        float a0 = acc[2 * k], a1 = acc[2 * k + 1];
        float o0 = __shfl_xor(a0, 1, 16);
        float o1 = __shfl_xor(a1, 1, 16);
        c8[k] = (l & 1) ? (a1 + o1) : (a0 + o0);
    }
    float c4[4];
#pragma unroll
    for (int k = 0; k < 4; ++k) {
        float a0 = c8[2 * k], a1 = c8[2 * k + 1];
        float o0 = __shfl_xor(a0, 2, 16);
        float o1 = __shfl_xor(a1, 2, 16);
        c4[k] = (l & 2) ? (a1 + o1) : (a0 + o0);
    }
    float c2[2];
#pragma unroll
    for (int k = 0; k < 2; ++k) {
        float a0 = c4[2 * k], a1 = c4[2 * k + 1];
        float o0 = __shfl_xor(a0, 4, 16);
        float o1 = __shfl_xor(a1, 4, 16);
        c2[k] = (l & 4) ? (a1 + o1) : (a0 + o0);
    }
    float a0 = c2[0], a1 = c2[1];
    float o0 = __shfl_xor(a0, 8, 16);
    float o1 = __shfl_xor(a1, 8, 16);
    float tot = (l & 8) ? (a1 + o1) : (a0 + o0);

    float self = xws[(size_t)node * HID + l];
    float v = fmaf(dinv[node], tot + self, b1[l]);
    out1[(size_t)node * HID + l] = fmaxf(v, 0.f);
}

// ---- h2s = (out1 @ W2) * dinv ---------------------------------------------
__global__ void k_layer2(const float* __restrict__ out1, const float* __restrict__ W2,
                         const float* __restrict__ dinv, float* __restrict__ h2s) {
    int i = blockIdx.x * blockDim.x + threadIdx.x;
    if (i >= N_NODES) return;
    const float4* hv = (const float4*)(out1 + (size_t)i * HID);
    float g0 = 0.f, g1 = 0.f;
#pragma unroll
    for (int q = 0; q < 4; ++q) {
        float4 v = hv[q];
        g0 = fmaf(v.x, W2[(4 * q + 0) * 2 + 0], g0);
        g1 = fmaf(v.x, W2[(4 * q + 0) * 2 + 1], g1);
        g0 = fmaf(v.y, W2[(4 * q + 1) * 2 + 0], g0);
        g1 = fmaf(v.y, W2[(4 * q + 1) * 2 + 1], g1);
        g0 = fmaf(v.z, W2[(4 * q + 2) * 2 + 0], g0);
        g1 = fmaf(v.z, W2[(4 * q + 2) * 2 + 1], g1);
        g0 = fmaf(v.w, W2[(4 * q + 3) * 2 + 0], g0);
        g1 = fmaf(v.w, W2[(4 * q + 3) * 2 + 1], g1);
    }
    float di = dinv[i];
    ((float2*)h2s)[i] = make_float2(g0 * di, g1 * di);
}

// ---- layer-2 aggregation + log_softmax: 16 lanes/node, NO atomics ----------
__global__ __launch_bounds__(256)
void k_gather2(const int* __restrict__ noff, const int* __restrict__ colf,
               const float* __restrict__ dinv, const float* __restrict__ h2s,
               const float* __restrict__ b2, float* __restrict__ y) {
    int t = blockIdx.x * 256 + threadIdx.x;
    int node = t >> 4;
    int l = t & 15;
    int start = noff[node], end = noff[node + 1];
    const float2* h2v = (const float2*)h2s;
    float g0 = 0.f, g1 = 0.f;
    for (int j = start; j < end; j += 16) {
        int jl = j + l;
        int jj = min(jl, end - 1);
        int s = colf[jj];
        s = (jl < end) ? s : N_NODES;
        float2 hv = h2v[s];
        g0 += hv.x; g1 += hv.y;
    }
#pragma unroll
    for (int d = 1; d < 16; d <<= 1) {
        g0 += __shfl_xor(g0, d, 16);
        g1 += __shfl_xor(g1, d, 16);
    }
    if (l == 0) {
        float2 self = h2v[node];
        float di = dinv[node];
        float v0 = fmaf(di, g0 + self.x, b2[0]);
        float v1 = fmaf(di, g1 + self.y, b2[1]);
        float m = fmaxf(v0, v1);
        float lse = m + logf(expf(v0 - m) + expf(v1 - m));
        ((float2*)y)[node] = make_float2(v0 - lse, v1 - lse);
    }
}

extern "C" void kernel_launch(void* const* d_in, const int* in_sizes, int n_in,
                              void* d_out, int out_size, void* d_ws, size_t ws_size,
                              hipStream_t stream) {
    const float* x  = (const float*)d_in[0];
    const void*  ei = d_in[1];
    const float* W1 = (const float*)d_in[2];
    const float* b1 = (const float*)d_in[3];
    const float* W2 = (const float*)d_in[4];
    const float* b2 = (const float*)d_in[5];
    float* y = (float*)d_out;

    char* w = (char*)d_ws;
    int*      flag    = (int*)(w + 0);
    int*      ghist   = (int*)(w + 1024);        // NB ints
    int*      goff    = (int*)(w + 8192);        // NB+1 ints
    int*      gcursor = (int*)(w + 16384);       // NB ints
    float*    dinv    = (float*)(w + 24576);     // 400 KB
    int*      noff    = (int*)(w + 425984);      // (N+1) ints
    unsigned* colp    = (unsigned*)(w + 828416); // 12.8 MB (dead after nodecsr)
    float*    xws     = (float*)(w + 828416);    // ALIAS over colp; (N+1)x16 f32
    float*    out1    = (float*)(w + 7228480);   // 6.4 MB (still inside colp+gap)
    int*      colf    = (int*)(w + 13631488);    // 12.8 MB
    float*    h2s     = (float*)(w + 26433536);  // (N+1)x2 f32
    // total ws use: ~27.3 MB

    hipMemsetAsync(ghist, 0, NB * sizeof(int), stream);
    hipMemsetAsync(h2s + (size_t)N_NODES * 2, 0, 2 * sizeof(float), stream);
    k_detect<<<1, 64, 0, stream>>>(ei, flag);
    k_hist<<<512, 256, 0, stream>>>(ei, flag, ghist);
    k_scan<<<1, 1024, 0, stream>>>(ghist, goff, gcursor);
    k_sortscatter<<<NCHUNKS, 1024, 0, stream>>>(ei, flag, gcursor, colp);
    k_nodecsr<<<NB, 256, 0, stream>>>(goff, colp, noff, colf, dinv);
    // colp is dead from here; xws aliases it. Zero the sentinel row now.
    hipMemsetAsync(xws + (size_t)N_NODES * HID, 0, HID * sizeof(float), stream);
    k_gemm1<<<(N_NODES + 255) / 256, 256, 0, stream>>>(x, W1, dinv, xws);
    k_gather1<<<(N_NODES * 16) / 256, 256, 0, stream>>>(noff, colf, dinv, xws, b1, out1);
    k_layer2<<<(N_NODES + 255) / 256, 256, 0, stream>>>(out1, W2, dinv, h2s);
    k_gather2<<<(N_NODES * 16) / 256, 256, 0, stream>>>(noff, colf, dinv, h2s, b2, y);
}